// Round 6
// baseline (239.796 us; speedup 1.0000x reference)
//
#include <hip/hip_runtime.h>
#include <math.h>

#define B_ 4
#define C_ 128
#define CI_ 64
#define H_ 96
#define W_ 96
#define HW_ (H_*W_)      // 9216
#define NP_ 2304         // 48*48
#define GROUPS_ 32
#define EPS_ 1e-5f
#define SPLIT_ 4
#define TPW_ 9           // KV tiles per wave = 36 / SPLIT_

typedef _Float16 f16x8 __attribute__((ext_vector_type(8)));
typedef _Float16 f16x2 __attribute__((ext_vector_type(2)));
typedef __attribute__((ext_vector_type(4))) float f32x4;

__device__ inline f32x4 mfma16h(f16x8 a, f16x8 b, f32x4 c) {
    return __builtin_amdgcn_mfma_f32_16x16x32_f16(a, b, c, 0, 0, 0);
}
__device__ inline float h2f(unsigned short s) {
    return (float)__builtin_bit_cast(_Float16, s);
}
__device__ inline unsigned pk_f16(float a, float b) {     // pack 2 f32 -> 2 f16 (RTZ)
    return __builtin_bit_cast(unsigned, __builtin_amdgcn_cvt_pkrtz(a, b));
}

// ---------------------------------------------------------------------------
// Kernel 1: fused 3-way 1x1 conv projections -> fp16 [b][n][ci]
// ---------------------------------------------------------------------------
__global__ __launch_bounds__(256) void proj_kernel(
    const float* __restrict__ x,
    const float* __restrict__ w_theta, const float* __restrict__ b_theta,
    const float* __restrict__ w_phi,   const float* __restrict__ b_phi,
    const float* __restrict__ w_g,     const float* __restrict__ b_g,
    unsigned short* __restrict__ Qo, unsigned short* __restrict__ phiF,
    unsigned short* __restrict__ gF)
{
    __shared__ float xs[C_ * 32];   // xs[c*32 + pix]
    __shared__ float ws[C_ * 68];   // ws[c*68 + ci]
    const int t    = threadIdx.x;
    const int tile = blockIdx.x;
    const int b    = blockIdx.y;
    const int mat  = blockIdx.z;
    const float* wsel = (mat == 0) ? w_theta : (mat == 1) ? w_phi : w_g;
    const float* bsel = (mat == 0) ? b_theta : (mat == 1) ? b_phi : b_g;
    unsigned short* osel = (mat == 0) ? Qo : (mat == 1) ? phiF : gF;
    const int n0 = tile * 32;

    {
        const int pix = t & 31;
        const int c0  = t >> 5;
        const float* xb = x + (size_t)b * C_ * HW_ + n0 + pix;
        for (int c = c0; c < C_; c += 8)
            xs[c * 32 + pix] = xb[(size_t)c * HW_];
    }
    for (int j = t; j < CI_ * C_; j += 256)
        ws[(j & 127) * 68 + (j >> 7)] = wsel[j];
    __syncthreads();

    const int tp = (t & 7) * 4;
    const int tc = (t >> 3) * 2;
    float acc[4][2] = {};
    #pragma unroll 4
    for (int c = 0; c < C_; ++c) {
        const float4 xv = *(const float4*)&xs[c * 32 + tp];
        const float2 wv = *(const float2*)&ws[c * 68 + tc];
        const float xa[4] = {xv.x, xv.y, xv.z, xv.w};
        #pragma unroll
        for (int i = 0; i < 4; ++i) {
            acc[i][0] += xa[i] * wv.x;
            acc[i][1] += xa[i] * wv.y;
        }
    }
    const float2 bb = *(const float2*)&bsel[tc];
    #pragma unroll
    for (int i = 0; i < 4; ++i) {
        f16x2 hv = { (_Float16)(acc[i][0] + bb.x), (_Float16)(acc[i][1] + bb.y) };
        *(f16x2*)&osel[((size_t)b * HW_ + n0 + tp + i) * CI_ + tc] = hv;
    }
}

// ---------------------------------------------------------------------------
// Kernel 2: 2x2 maxpool (fp16 in/out, exact). K stays [b][m][ci]; V -> [b][ci][m].
// ---------------------------------------------------------------------------
__global__ __launch_bounds__(256) void pool_kernel(
    const unsigned short* __restrict__ phiF, const unsigned short* __restrict__ gF,
    unsigned short* __restrict__ Ko, unsigned short* __restrict__ Vt)
{
    const int t   = threadIdx.x;
    const int b   = blockIdx.y;
    const int mat = blockIdx.z;                 // 0 -> K, 1 -> V^T
    const int idx = blockIdx.x * 256 + t;       // 0..147455
    int m, ci;
    if (mat == 0) { m = idx >> 6; ci = idx & 63; }
    else          { ci = idx / NP_; m = idx - ci * NP_; }
    const int ph = m / 48, pw = m % 48;
    const int n00 = (ph * 2) * W_ + pw * 2;
    const unsigned short* src = mat ? gF : phiF;
    const unsigned short* p = src + ((size_t)b * HW_ + n00) * CI_ + ci;
    float v = fmaxf(fmaxf(h2f(p[0]), h2f(p[CI_])),
                    fmaxf(h2f(p[(size_t)W_ * CI_]), h2f(p[(size_t)(W_ + 1) * CI_])));
    unsigned short r = __builtin_bit_cast(unsigned short, (_Float16)v); // exact
    if (mat == 0) Ko[((size_t)b * NP_ + m) * CI_ + ci] = r;
    else          Vt[((size_t)b * CI_ + ci) * NP_ + m] = r;
}

// ---------------------------------------------------------------------------
// Kernel 3: fp16 MFMA flash attention, SPLIT-KV.
// Block = 4 waves, each wave: SAME 32 q-rows, DISJOINT 9-tile KV slice
// (barrier-free main loop). Exact LDS combine at the end:
//   m_g = max_w m_w ; O_g = sum_w O_w*exp(m_w-m_g) ; l_g = sum_w l_w*exp(m_w-m_g).
// K/V read directly from global (L2-resident). Per-wave P-repack LDS buffer
// aliases the wave's own O-combine slice (dead until the wave's loop is done).
// ---------------------------------------------------------------------------
__global__ __launch_bounds__(256, 4) void attn_kernel(
    const unsigned short* __restrict__ Qg, const unsigned short* __restrict__ Kg,
    const unsigned short* __restrict__ Vt, float* __restrict__ Yg)
{
    __shared__ float Olds[SPLIT_ * 32 * 68];     // 34816 B; per-wave slice 8704 B
    __shared__ float ml[SPLIT_][32][2];          // 1024 B

    const int t    = threadIdx.x;
    const int wv   = t >> 6;
    const int lane = t & 63;
    const int lr   = lane & 15;
    const int lg   = lane >> 4;
    const int b    = blockIdx.y;
    const int q0   = blockIdx.x * 32;

    unsigned char* Ps = (unsigned char*)&Olds[wv * 32 * 68];  // 2304 B used

    const unsigned short* Kb = Kg + (size_t)b * NP_ * CI_;
    const unsigned short* Vb = Vt + (size_t)b * CI_ * NP_;

    // Q fragments in registers: qs in {0,1} sub-tiles, u in {0,1} k-steps
    f16x8 qf[2][2];
    #pragma unroll
    for (int qs = 0; qs < 2; ++qs)
        #pragma unroll
        for (int u = 0; u < 2; ++u)
            qf[qs][u] = *(const f16x8*)(Qg
                + ((size_t)b * HW_ + q0 + qs * 16 + lr) * CI_ + u * 32 + lg * 8);

    f32x4 o_acc[2][4];
    #pragma unroll
    for (int qs = 0; qs < 2; ++qs)
        #pragma unroll
        for (int dt = 0; dt < 4; ++dt)
            o_acc[qs][dt] = (f32x4){0.f, 0.f, 0.f, 0.f};
    float mrun[2] = {-1e30f, -1e30f};
    float lrun[2] = {0.f, 0.f};

    #pragma unroll 1
    for (int kt = wv * TPW_; kt < wv * TPW_ + TPW_; ++kt) {
        const int kv0 = kt * 64;
        f16x8 kc[8], vcur[8];
        #pragma unroll
        for (int u = 0; u < 2; ++u) {
            #pragma unroll
            for (int k4 = 0; k4 < 4; ++k4)
                kc[u * 4 + k4] = *(const f16x8*)(Kb
                    + (size_t)(kv0 + k4 * 16 + lr) * CI_ + u * 32 + lg * 8);
            #pragma unroll
            for (int dt = 0; dt < 4; ++dt)
                vcur[u * 4 + dt] = *(const f16x8*)(Vb
                    + (size_t)(dt * 16 + lr) * NP_ + kv0 + u * 32 + lg * 8);
        }

        #pragma unroll
        for (int qs = 0; qs < 2; ++qs) {
            // ---- S^T = K * Q^T : lane holds S[k = 16*k4 + 4*lg + r][q = lr]
            f32x4 s[4];
            #pragma unroll
            for (int k4 = 0; k4 < 4; ++k4) s[k4] = (f32x4){0.f, 0.f, 0.f, 0.f};
            __builtin_amdgcn_s_setprio(1);
            #pragma unroll
            for (int u = 0; u < 2; ++u)
                #pragma unroll
                for (int k4 = 0; k4 < 4; ++k4)
                    s[k4] = mfma16h(kc[u * 4 + k4], qf[qs][u], s[k4]);
            __builtin_amdgcn_s_setprio(0);

            // ---- online softmax with defer-max (THR=8)
            float tmax = -1e30f;
            #pragma unroll
            for (int k4 = 0; k4 < 4; ++k4)
                tmax = fmaxf(tmax, fmaxf(fmaxf(s[k4][0], s[k4][1]),
                                         fmaxf(s[k4][2], s[k4][3])));
            tmax = fmaxf(tmax, __shfl_xor(tmax, 16));
            tmax = fmaxf(tmax, __shfl_xor(tmax, 32));

            if (!__all(tmax <= mrun[qs] + 8.0f)) {
                const float mnew = fmaxf(mrun[qs], tmax);
                const float sc = __expf(mrun[qs] - mnew);
                lrun[qs] *= sc;
                #pragma unroll
                for (int r2 = 0; r2 < 4; ++r2) {
                    const float scb = __shfl(sc, 4 * lg + r2);
                    #pragma unroll
                    for (int dt = 0; dt < 4; ++dt) o_acc[qs][dt][r2] *= scb;
                }
                mrun[qs] = mnew;
            }

            float pv[16];
            float tsum = 0.f;
            #pragma unroll
            for (int k4 = 0; k4 < 4; ++k4)
                #pragma unroll
                for (int r = 0; r < 4; ++r) {
                    const float e = __expf(s[k4][r] - mrun[qs]);
                    pv[k4 * 4 + r] = e;
                    tsum += e;
                }
            tsum += __shfl_xor(tsum, 16);
            tsum += __shfl_xor(tsum, 32);
            lrun[qs] += tsum;

            // ---- P -> LDS (fp16, PV A-fragment layout [q][k], 144B stride)
            #pragma unroll
            for (int k4 = 0; k4 < 4; ++k4) {
                uint2 pk = { pk_f16(pv[k4 * 4 + 0], pv[k4 * 4 + 1]),
                             pk_f16(pv[k4 * 4 + 2], pv[k4 * 4 + 3]) };
                *(uint2*)&Ps[lr * 144 + k4 * 32 + lg * 8] = pk;
            }

            // ---- O += P * V
            #pragma unroll
            for (int u = 0; u < 2; ++u) {
                f16x8 pfr = *(const f16x8*)&Ps[lr * 144 + 64 * u + 16 * lg];
                __builtin_amdgcn_s_setprio(1);
                #pragma unroll
                for (int dt = 0; dt < 4; ++dt)
                    o_acc[qs][dt] = mfma16h(pfr, vcur[u * 4 + dt], o_acc[qs][dt]);
                __builtin_amdgcn_s_setprio(0);
            }
        }
    }

    // ---- combine the 4 KV-slices -------------------------------------------
    asm volatile("" ::: "memory");               // order Ps reads vs Olds writes
    if (lg == 0) {
        #pragma unroll
        for (int qs = 0; qs < 2; ++qs) {
            ml[wv][qs * 16 + lr][0] = mrun[qs];
            ml[wv][qs * 16 + lr][1] = lrun[qs];
        }
    }
    __syncthreads();

    #pragma unroll
    for (int qs = 0; qs < 2; ++qs) {
        const int row = qs * 16 + lr;
        const float mg = fmaxf(fmaxf(ml[0][row][0], ml[1][row][0]),
                               fmaxf(ml[2][row][0], ml[3][row][0]));
        const float fac = __expf(mrun[qs] - mg);
        #pragma unroll
        for (int r2 = 0; r2 < 4; ++r2) {
            const float fb = __shfl(fac, 4 * lg + r2);
            #pragma unroll
            for (int dt = 0; dt < 4; ++dt)
                Olds[wv * 32 * 68 + (qs * 16 + 4 * lg + r2) * 68 + dt * 16 + lr]
                    = o_acc[qs][dt][r2] * fb;
        }
    }
    __syncthreads();

    {   // 256 threads: 8 output elems each (row = t>>3, cols = (t&7)*8 ..+7)
        const int row = t >> 3;
        const int c0  = (t & 7) * 8;
        const float m0 = ml[0][row][0], m1 = ml[1][row][0],
                    m2 = ml[2][row][0], m3 = ml[3][row][0];
        const float mg = fmaxf(fmaxf(m0, m1), fmaxf(m2, m3));
        const float sumL = ml[0][row][1] * __expf(m0 - mg)
                         + ml[1][row][1] * __expf(m1 - mg)
                         + ml[2][row][1] * __expf(m2 - mg)
                         + ml[3][row][1] * __expf(m3 - mg);
        const float inv = 1.0f / sumL;
        float4 a0 = {0.f, 0.f, 0.f, 0.f}, a1 = {0.f, 0.f, 0.f, 0.f};
        #pragma unroll
        for (int w = 0; w < 4; ++w) {
            const float4 v0 = *(const float4*)&Olds[w * 32 * 68 + row * 68 + c0];
            const float4 v1 = *(const float4*)&Olds[w * 32 * 68 + row * 68 + c0 + 4];
            a0.x += v0.x; a0.y += v0.y; a0.z += v0.z; a0.w += v0.w;
            a1.x += v1.x; a1.y += v1.y; a1.z += v1.z; a1.w += v1.w;
        }
        float* yp = Yg + ((size_t)b * HW_ + q0 + row) * CI_ + c0;
        float4 r0 = { a0.x * inv, a0.y * inv, a0.z * inv, a0.w * inv };
        float4 r1 = { a1.x * inv, a1.y * inv, a1.z * inv, a1.w * inv };
        *(float4*)yp       = r0;
        *(float4*)(yp + 4) = r1;
    }
}

// ---------------------------------------------------------------------------
// Kernel 4: 1x1 conv back to 128 channels (fp32).
// ---------------------------------------------------------------------------
__global__ __launch_bounds__(256) void conv2_kernel(
    const float* __restrict__ Yg, const float* __restrict__ wW,
    const float* __restrict__ bW, float* __restrict__ Zg)
{
    __shared__ float ys[CI_ * 68];
    __shared__ float ws2[CI_ * 132];
    const int t  = threadIdx.x;
    const int b  = blockIdx.y;
    const int n0 = blockIdx.x * 64;

    const float* ybase = Yg + ((size_t)b * HW_ + n0) * CI_;
    for (int j = t; j < 64 * CI_; j += 256)
        ys[(j & 63) * 68 + (j >> 6)] = ybase[j];
    for (int j = t; j < C_ * CI_; j += 256)
        ws2[(j & 63) * 132 + (j >> 6)] = wW[j];
    __syncthreads();

    const int tp = (t & 15) * 4;
    const int to = (t >> 4) * 8;
    float acc[4][8] = {};
    #pragma unroll 2
    for (int ci = 0; ci < CI_; ++ci) {
        const float4 yv  = *(const float4*)&ys[ci * 68 + tp];
        const float4 wv0 = *(const float4*)&ws2[ci * 132 + to];
        const float4 wv1 = *(const float4*)&ws2[ci * 132 + to + 4];
        const float ya[4] = {yv.x, yv.y, yv.z, yv.w};
        const float wa[8] = {wv0.x, wv0.y, wv0.z, wv0.w, wv1.x, wv1.y, wv1.z, wv1.w};
        #pragma unroll
        for (int i = 0; i < 4; ++i)
            #pragma unroll
            for (int j = 0; j < 8; ++j)
                acc[i][j] += ya[i] * wa[j];
    }
    #pragma unroll
    for (int j = 0; j < 8; ++j) {
        const int o = to + j;
        const float bb = bW[o];
        float* zp = Zg + ((size_t)b * C_ + o) * HW_ + n0 + tp;
        float4 v = { acc[0][j] + bb, acc[1][j] + bb, acc[2][j] + bb, acc[3][j] + bb };
        *(float4*)zp = v;
    }
}

// ---------------------------------------------------------------------------
// Kernel 5: GroupNorm stats (deterministic).
// ---------------------------------------------------------------------------
__global__ __launch_bounds__(256) void stats_kernel(
    const float* __restrict__ Zg, float* __restrict__ stats)
{
    const int t  = threadIdx.x;
    const int gr = blockIdx.x;
    const int b  = blockIdx.y;
    const float4* zp = (const float4*)(Zg + ((size_t)b * C_ + gr * 4) * HW_);
    float s = 0.f, ss = 0.f;
    for (int i = t; i < HW_; i += 256) {
        const float4 v = zp[i];
        s  += v.x + v.y + v.z + v.w;
        ss += v.x*v.x + v.y*v.y + v.z*v.z + v.w*v.w;
    }
    __shared__ float rs[256], rq[256];
    rs[t] = s; rq[t] = ss;
    __syncthreads();
    for (int off = 128; off > 0; off >>= 1) {
        if (t < off) { rs[t] += rs[t + off]; rq[t] += rq[t + off]; }
        __syncthreads();
    }
    if (t == 0) {
        const float invn = 1.0f / (4 * HW_);
        const float mean = rs[0] * invn;
        const float var  = rq[0] * invn - mean * mean;
        stats[((size_t)b * GROUPS_ + gr) * 2 + 0] = mean;
        stats[((size_t)b * GROUPS_ + gr) * 2 + 1] = rsqrtf(var + EPS_);
    }
}

// ---------------------------------------------------------------------------
// Kernel 6: normalize + affine + residual.
// ---------------------------------------------------------------------------
__global__ __launch_bounds__(256) void final_kernel(
    const float* __restrict__ Zg, const float* __restrict__ xg,
    const float* __restrict__ stats, const float* __restrict__ gnw,
    const float* __restrict__ gnb, float* __restrict__ out)
{
    const size_t i4  = (size_t)blockIdx.x * 256 + threadIdx.x;
    const size_t idx = i4 * 4;
    const int bc = (int)(i4 / (HW_ / 4));
    const int c  = bc & 127;
    const int b  = bc >> 7;
    const int g  = c >> 2;
    const float mean = stats[((size_t)b * GROUPS_ + g) * 2 + 0];
    const float rstd = stats[((size_t)b * GROUPS_ + g) * 2 + 1];
    const float sc = rstd * gnw[c];
    const float sh = gnb[c] - mean * sc;
    const float4 z  = *(const float4*)(Zg + idx);
    const float4 xv = *(const float4*)(xg + idx);
    float4 o;
    o.x = z.x * sc + sh + xv.x;
    o.y = z.y * sc + sh + xv.y;
    o.z = z.z * sc + sh + xv.z;
    o.w = z.w * sc + sh + xv.w;
    *(float4*)(out + idx) = o;
}

// ---------------------------------------------------------------------------
extern "C" void kernel_launch(void* const* d_in, const int* in_sizes, int n_in,
                              void* d_out, int out_size, void* d_ws, size_t ws_size,
                              hipStream_t stream)
{
    const float* x       = (const float*)d_in[0];
    const float* w_theta = (const float*)d_in[1];
    const float* b_theta = (const float*)d_in[2];
    const float* w_phi   = (const float*)d_in[3];
    const float* b_phi   = (const float*)d_in[4];
    const float* w_g     = (const float*)d_in[5];
    const float* b_g     = (const float*)d_in[6];
    const float* w_W     = (const float*)d_in[7];
    const float* b_W     = (const float*)d_in[8];
    const float* gn_w    = (const float*)d_in[9];
    const float* gn_b    = (const float*)d_in[10];
    float* out = (float*)d_out;
    char* wsb  = (char*)d_ws;

    // workspace layout (bytes)
    unsigned short* Q    = (unsigned short*)(wsb);             //  4,718,592
    unsigned short* K    = (unsigned short*)(wsb +  4718592);  //  1,179,648
    unsigned short* Vt   = (unsigned short*)(wsb +  5898240);  //  1,179,648
    unsigned short* phiF = (unsigned short*)(wsb +  7077888);  //  4,718,592
    unsigned short* gF   = (unsigned short*)(wsb + 11796480);  //  4,718,592
    float* Y             = (float*)(wsb +  7077888);           //  9,437,184 (aliases phiF+gF, dead after pool)
    float* Z             = (float*)(wsb + 16515072);           // 18,874,368
    float* stats         = (float*)(wsb + 35389440);           //  1 KB

    proj_kernel <<<dim3(HW_ / 32, B_, 3), 256, 0, stream>>>(
        x, w_theta, b_theta, w_phi, b_phi, w_g, b_g, Q, phiF, gF);
    pool_kernel <<<dim3(NP_ * CI_ / 256, B_, 2), 256, 0, stream>>>(phiF, gF, K, Vt);
    attn_kernel <<<dim3(HW_ / 32, B_), 256, 0, stream>>>(Q, K, Vt, Y);
    conv2_kernel<<<dim3(HW_ / 64, B_), 256, 0, stream>>>(Y, w_W, b_W, Z);
    stats_kernel<<<dim3(GROUPS_, B_), 256, 0, stream>>>(Z, stats);
    final_kernel<<<dim3((B_ * C_ * HW_) / 1024, 1), 256, 0, stream>>>(
        Z, x, stats, gn_w, gn_b, out);
}

// Round 7
// 182.413 us; speedup vs baseline: 1.3146x; 1.3146x over previous
//
#include <hip/hip_runtime.h>
#include <math.h>

#define B_ 4
#define C_ 128
#define CI_ 64
#define H_ 96
#define W_ 96
#define HW_ (H_*W_)      // 9216
#define NP_ 2304         // 48*48
#define GROUPS_ 32
#define EPS_ 1e-5f
#define SPLIT_ 4
#define TPW_ 9           // KV tiles per wave = 36 / SPLIT_

typedef _Float16 f16x8 __attribute__((ext_vector_type(8)));
typedef _Float16 f16x2 __attribute__((ext_vector_type(2)));
typedef __attribute__((ext_vector_type(4))) float f32x4;

__device__ inline f32x4 mfma16h(f16x8 a, f16x8 b, f32x4 c) {
    return __builtin_amdgcn_mfma_f32_16x16x32_f16(a, b, c, 0, 0, 0);
}
__device__ inline float h2f(unsigned short s) {
    return (float)__builtin_bit_cast(_Float16, s);
}
__device__ inline unsigned pk_f16(float a, float b) {     // pack 2 f32 -> 2 f16 (RTZ)
    return __builtin_bit_cast(unsigned, __builtin_amdgcn_cvt_pkrtz(a, b));
}

// ---------------------------------------------------------------------------
// Kernel 1: fused 3-way 1x1 conv projections -> fp16 [b][n][ci]
// ---------------------------------------------------------------------------
__global__ __launch_bounds__(256) void proj_kernel(
    const float* __restrict__ x,
    const float* __restrict__ w_theta, const float* __restrict__ b_theta,
    const float* __restrict__ w_phi,   const float* __restrict__ b_phi,
    const float* __restrict__ w_g,     const float* __restrict__ b_g,
    unsigned short* __restrict__ Qo, unsigned short* __restrict__ phiF,
    unsigned short* __restrict__ gF)
{
    __shared__ float xs[C_ * 32];   // xs[c*32 + pix]
    __shared__ float ws[C_ * 68];   // ws[c*68 + ci]
    const int t    = threadIdx.x;
    const int tile = blockIdx.x;
    const int b    = blockIdx.y;
    const int mat  = blockIdx.z;
    const float* wsel = (mat == 0) ? w_theta : (mat == 1) ? w_phi : w_g;
    const float* bsel = (mat == 0) ? b_theta : (mat == 1) ? b_phi : b_g;
    unsigned short* osel = (mat == 0) ? Qo : (mat == 1) ? phiF : gF;
    const int n0 = tile * 32;

    {
        const int pix = t & 31;
        const int c0  = t >> 5;
        const float* xb = x + (size_t)b * C_ * HW_ + n0 + pix;
        for (int c = c0; c < C_; c += 8)
            xs[c * 32 + pix] = xb[(size_t)c * HW_];
    }
    for (int j = t; j < CI_ * C_; j += 256)
        ws[(j & 127) * 68 + (j >> 7)] = wsel[j];
    __syncthreads();

    const int tp = (t & 7) * 4;
    const int tc = (t >> 3) * 2;
    float acc[4][2] = {};
    #pragma unroll 4
    for (int c = 0; c < C_; ++c) {
        const float4 xv = *(const float4*)&xs[c * 32 + tp];
        const float2 wv = *(const float2*)&ws[c * 68 + tc];
        const float xa[4] = {xv.x, xv.y, xv.z, xv.w};
        #pragma unroll
        for (int i = 0; i < 4; ++i) {
            acc[i][0] += xa[i] * wv.x;
            acc[i][1] += xa[i] * wv.y;
        }
    }
    const float2 bb = *(const float2*)&bsel[tc];
    #pragma unroll
    for (int i = 0; i < 4; ++i) {
        f16x2 hv = { (_Float16)(acc[i][0] + bb.x), (_Float16)(acc[i][1] + bb.y) };
        *(f16x2*)&osel[((size_t)b * HW_ + n0 + tp + i) * CI_ + tc] = hv;
    }
}

// ---------------------------------------------------------------------------
// Kernel 2: 2x2 maxpool (fp16 in/out, exact). K stays [b][m][ci]; V -> [b][ci][m].
// ---------------------------------------------------------------------------
__global__ __launch_bounds__(256) void pool_kernel(
    const unsigned short* __restrict__ phiF, const unsigned short* __restrict__ gF,
    unsigned short* __restrict__ Ko, unsigned short* __restrict__ Vt)
{
    const int t   = threadIdx.x;
    const int b   = blockIdx.y;
    const int mat = blockIdx.z;                 // 0 -> K, 1 -> V^T
    const int idx = blockIdx.x * 256 + t;       // 0..147455
    int m, ci;
    if (mat == 0) { m = idx >> 6; ci = idx & 63; }
    else          { ci = idx / NP_; m = idx - ci * NP_; }
    const int ph = m / 48, pw = m % 48;
    const int n00 = (ph * 2) * W_ + pw * 2;
    const unsigned short* src = mat ? gF : phiF;
    const unsigned short* p = src + ((size_t)b * HW_ + n00) * CI_ + ci;
    float v = fmaxf(fmaxf(h2f(p[0]), h2f(p[CI_])),
                    fmaxf(h2f(p[(size_t)W_ * CI_]), h2f(p[(size_t)(W_ + 1) * CI_])));
    unsigned short r = __builtin_bit_cast(unsigned short, (_Float16)v); // exact
    if (mat == 0) Ko[((size_t)b * NP_ + m) * CI_ + ci] = r;
    else          Vt[((size_t)b * CI_ + ci) * NP_ + m] = r;
}

// ---------------------------------------------------------------------------
// Kernel 3: fp16 MFMA flash attention, SPLIT-KV.
// Block = 4 waves, each wave: SAME 32 q-rows, DISJOINT 9-tile KV slice
// (barrier-free main loop). Exact LDS combine at the end.
// __launch_bounds__(256,2): VGPR cap 256 — the kernel needs ~160 live regs
// (R6's (256,4) forced 64 VGPRs -> 122 MB of scratch spill traffic).
// ---------------------------------------------------------------------------
__global__ __launch_bounds__(256, 2) void attn_kernel(
    const unsigned short* __restrict__ Qg, const unsigned short* __restrict__ Kg,
    const unsigned short* __restrict__ Vt, float* __restrict__ Yg)
{
    __shared__ float Olds[SPLIT_ * 32 * 68];     // 34816 B; per-wave slice 8704 B
    __shared__ float ml[SPLIT_][32][2];          // 1024 B

    const int t    = threadIdx.x;
    const int wv   = t >> 6;
    const int lane = t & 63;
    const int lr   = lane & 15;
    const int lg   = lane >> 4;
    const int b    = blockIdx.y;
    const int q0   = blockIdx.x * 32;

    unsigned char* Ps = (unsigned char*)&Olds[wv * 32 * 68];  // 2304 B used

    const unsigned short* Kb = Kg + (size_t)b * NP_ * CI_;
    const unsigned short* Vb = Vt + (size_t)b * CI_ * NP_;

    // Q fragments in registers: qs in {0,1} sub-tiles, u in {0,1} k-steps
    f16x8 qf[2][2];
    #pragma unroll
    for (int qs = 0; qs < 2; ++qs)
        #pragma unroll
        for (int u = 0; u < 2; ++u)
            qf[qs][u] = *(const f16x8*)(Qg
                + ((size_t)b * HW_ + q0 + qs * 16 + lr) * CI_ + u * 32 + lg * 8);

    f32x4 o_acc[2][4];
    #pragma unroll
    for (int qs = 0; qs < 2; ++qs)
        #pragma unroll
        for (int dt = 0; dt < 4; ++dt)
            o_acc[qs][dt] = (f32x4){0.f, 0.f, 0.f, 0.f};
    float mrun[2] = {-1e30f, -1e30f};
    float lrun[2] = {0.f, 0.f};

    #pragma unroll 1
    for (int kt = wv * TPW_; kt < wv * TPW_ + TPW_; ++kt) {
        const int kv0 = kt * 64;
        f16x8 kc[8], vcur[8];
        #pragma unroll
        for (int u = 0; u < 2; ++u) {
            #pragma unroll
            for (int k4 = 0; k4 < 4; ++k4)
                kc[u * 4 + k4] = *(const f16x8*)(Kb
                    + (size_t)(kv0 + k4 * 16 + lr) * CI_ + u * 32 + lg * 8);
            #pragma unroll
            for (int dt = 0; dt < 4; ++dt)
                vcur[u * 4 + dt] = *(const f16x8*)(Vb
                    + (size_t)(dt * 16 + lr) * NP_ + kv0 + u * 32 + lg * 8);
        }

        #pragma unroll
        for (int qs = 0; qs < 2; ++qs) {
            // ---- S^T = K * Q^T : lane holds S[k = 16*k4 + 4*lg + r][q = lr]
            f32x4 s[4];
            #pragma unroll
            for (int k4 = 0; k4 < 4; ++k4) s[k4] = (f32x4){0.f, 0.f, 0.f, 0.f};
            __builtin_amdgcn_s_setprio(1);
            #pragma unroll
            for (int u = 0; u < 2; ++u)
                #pragma unroll
                for (int k4 = 0; k4 < 4; ++k4)
                    s[k4] = mfma16h(kc[u * 4 + k4], qf[qs][u], s[k4]);
            __builtin_amdgcn_s_setprio(0);

            // ---- online softmax with defer-max (THR=8)
            float tmax = -1e30f;
            #pragma unroll
            for (int k4 = 0; k4 < 4; ++k4)
                tmax = fmaxf(tmax, fmaxf(fmaxf(s[k4][0], s[k4][1]),
                                         fmaxf(s[k4][2], s[k4][3])));
            tmax = fmaxf(tmax, __shfl_xor(tmax, 16));
            tmax = fmaxf(tmax, __shfl_xor(tmax, 32));

            if (!__all(tmax <= mrun[qs] + 8.0f)) {
                const float mnew = fmaxf(mrun[qs], tmax);
                const float sc = __expf(mrun[qs] - mnew);
                lrun[qs] *= sc;
                #pragma unroll
                for (int r2 = 0; r2 < 4; ++r2) {
                    const float scb = __shfl(sc, 4 * lg + r2);
                    #pragma unroll
                    for (int dt = 0; dt < 4; ++dt) o_acc[qs][dt][r2] *= scb;
                }
                mrun[qs] = mnew;
            }

            float pv[16];
            float tsum = 0.f;
            #pragma unroll
            for (int k4 = 0; k4 < 4; ++k4)
                #pragma unroll
                for (int r = 0; r < 4; ++r) {
                    const float e = __expf(s[k4][r] - mrun[qs]);
                    pv[k4 * 4 + r] = e;
                    tsum += e;
                }
            tsum += __shfl_xor(tsum, 16);
            tsum += __shfl_xor(tsum, 32);
            lrun[qs] += tsum;

            // ---- P -> LDS (fp16, PV A-fragment layout [q][k], 144B stride)
            #pragma unroll
            for (int k4 = 0; k4 < 4; ++k4) {
                uint2 pk = { pk_f16(pv[k4 * 4 + 0], pv[k4 * 4 + 1]),
                             pk_f16(pv[k4 * 4 + 2], pv[k4 * 4 + 3]) };
                *(uint2*)&Ps[lr * 144 + k4 * 32 + lg * 8] = pk;
            }

            // ---- O += P * V
            #pragma unroll
            for (int u = 0; u < 2; ++u) {
                f16x8 pfr = *(const f16x8*)&Ps[lr * 144 + 64 * u + 16 * lg];
                __builtin_amdgcn_s_setprio(1);
                #pragma unroll
                for (int dt = 0; dt < 4; ++dt)
                    o_acc[qs][dt] = mfma16h(pfr, vcur[u * 4 + dt], o_acc[qs][dt]);
                __builtin_amdgcn_s_setprio(0);
            }
        }
    }

    // ---- combine the 4 KV-slices -------------------------------------------
    asm volatile("" ::: "memory");               // order Ps reads vs Olds writes
    if (lg == 0) {
        #pragma unroll
        for (int qs = 0; qs < 2; ++qs) {
            ml[wv][qs * 16 + lr][0] = mrun[qs];
            ml[wv][qs * 16 + lr][1] = lrun[qs];
        }
    }
    __syncthreads();

    #pragma unroll
    for (int qs = 0; qs < 2; ++qs) {
        const int row = qs * 16 + lr;
        const float mg = fmaxf(fmaxf(ml[0][row][0], ml[1][row][0]),
                               fmaxf(ml[2][row][0], ml[3][row][0]));
        const float fac = __expf(mrun[qs] - mg);
        #pragma unroll
        for (int r2 = 0; r2 < 4; ++r2) {
            const float fb = __shfl(fac, 4 * lg + r2);
            #pragma unroll
            for (int dt = 0; dt < 4; ++dt)
                Olds[wv * 32 * 68 + (qs * 16 + 4 * lg + r2) * 68 + dt * 16 + lr]
                    = o_acc[qs][dt][r2] * fb;
        }
    }
    __syncthreads();

    {   // 256 threads: 8 output elems each (row = t>>3, cols = (t&7)*8 ..+7)
        const int row = t >> 3;
        const int c0  = (t & 7) * 8;
        const float m0 = ml[0][row][0], m1 = ml[1][row][0],
                    m2 = ml[2][row][0], m3 = ml[3][row][0];
        const float mg = fmaxf(fmaxf(m0, m1), fmaxf(m2, m3));
        const float sumL = ml[0][row][1] * __expf(m0 - mg)
                         + ml[1][row][1] * __expf(m1 - mg)
                         + ml[2][row][1] * __expf(m2 - mg)
                         + ml[3][row][1] * __expf(m3 - mg);
        const float inv = 1.0f / sumL;
        float4 a0 = {0.f, 0.f, 0.f, 0.f}, a1 = {0.f, 0.f, 0.f, 0.f};
        #pragma unroll
        for (int w = 0; w < 4; ++w) {
            const float4 v0 = *(const float4*)&Olds[w * 32 * 68 + row * 68 + c0];
            const float4 v1 = *(const float4*)&Olds[w * 32 * 68 + row * 68 + c0 + 4];
            a0.x += v0.x; a0.y += v0.y; a0.z += v0.z; a0.w += v0.w;
            a1.x += v1.x; a1.y += v1.y; a1.z += v1.z; a1.w += v1.w;
        }
        float* yp = Yg + ((size_t)b * HW_ + q0 + row) * CI_ + c0;
        float4 r0 = { a0.x * inv, a0.y * inv, a0.z * inv, a0.w * inv };
        float4 r1 = { a1.x * inv, a1.y * inv, a1.z * inv, a1.w * inv };
        *(float4*)yp       = r0;
        *(float4*)(yp + 4) = r1;
    }
}

// ---------------------------------------------------------------------------
// Kernel 4: 1x1 conv back to 128 channels (fp32).
// ---------------------------------------------------------------------------
__global__ __launch_bounds__(256) void conv2_kernel(
    const float* __restrict__ Yg, const float* __restrict__ wW,
    const float* __restrict__ bW, float* __restrict__ Zg)
{
    __shared__ float ys[CI_ * 68];
    __shared__ float ws2[CI_ * 132];
    const int t  = threadIdx.x;
    const int b  = blockIdx.y;
    const int n0 = blockIdx.x * 64;

    const float* ybase = Yg + ((size_t)b * HW_ + n0) * CI_;
    for (int j = t; j < 64 * CI_; j += 256)
        ys[(j & 63) * 68 + (j >> 6)] = ybase[j];
    for (int j = t; j < C_ * CI_; j += 256)
        ws2[(j & 63) * 132 + (j >> 6)] = wW[j];
    __syncthreads();

    const int tp = (t & 15) * 4;
    const int to = (t >> 4) * 8;
    float acc[4][8] = {};
    #pragma unroll 2
    for (int ci = 0; ci < CI_; ++ci) {
        const float4 yv  = *(const float4*)&ys[ci * 68 + tp];
        const float4 wv0 = *(const float4*)&ws2[ci * 132 + to];
        const float4 wv1 = *(const float4*)&ws2[ci * 132 + to + 4];
        const float ya[4] = {yv.x, yv.y, yv.z, yv.w};
        const float wa[8] = {wv0.x, wv0.y, wv0.z, wv0.w, wv1.x, wv1.y, wv1.z, wv1.w};
        #pragma unroll
        for (int i = 0; i < 4; ++i)
            #pragma unroll
            for (int j = 0; j < 8; ++j)
                acc[i][j] += ya[i] * wa[j];
    }
    #pragma unroll
    for (int j = 0; j < 8; ++j) {
        const int o = to + j;
        const float bb = bW[o];
        float* zp = Zg + ((size_t)b * C_ + o) * HW_ + n0 + tp;
        float4 v = { acc[0][j] + bb, acc[1][j] + bb, acc[2][j] + bb, acc[3][j] + bb };
        *(float4*)zp = v;
    }
}

// ---------------------------------------------------------------------------
// Kernel 5: GroupNorm stats (deterministic).
// ---------------------------------------------------------------------------
__global__ __launch_bounds__(256) void stats_kernel(
    const float* __restrict__ Zg, float* __restrict__ stats)
{
    const int t  = threadIdx.x;
    const int gr = blockIdx.x;
    const int b  = blockIdx.y;
    const float4* zp = (const float4*)(Zg + ((size_t)b * C_ + gr * 4) * HW_);
    float s = 0.f, ss = 0.f;
    for (int i = t; i < HW_; i += 256) {
        const float4 v = zp[i];
        s  += v.x + v.y + v.z + v.w;
        ss += v.x*v.x + v.y*v.y + v.z*v.z + v.w*v.w;
    }
    __shared__ float rs[256], rq[256];
    rs[t] = s; rq[t] = ss;
    __syncthreads();
    for (int off = 128; off > 0; off >>= 1) {
        if (t < off) { rs[t] += rs[t + off]; rq[t] += rq[t + off]; }
        __syncthreads();
    }
    if (t == 0) {
        const float invn = 1.0f / (4 * HW_);
        const float mean = rs[0] * invn;
        const float var  = rq[0] * invn - mean * mean;
        stats[((size_t)b * GROUPS_ + gr) * 2 + 0] = mean;
        stats[((size_t)b * GROUPS_ + gr) * 2 + 1] = rsqrtf(var + EPS_);
    }
}

// ---------------------------------------------------------------------------
// Kernel 6: normalize + affine + residual.
// ---------------------------------------------------------------------------
__global__ __launch_bounds__(256) void final_kernel(
    const float* __restrict__ Zg, const float* __restrict__ xg,
    const float* __restrict__ stats, const float* __restrict__ gnw,
    const float* __restrict__ gnb, float* __restrict__ out)
{
    const size_t i4  = (size_t)blockIdx.x * 256 + threadIdx.x;
    const size_t idx = i4 * 4;
    const int bc = (int)(i4 / (HW_ / 4));
    const int c  = bc & 127;
    const int b  = bc >> 7;
    const int g  = c >> 2;
    const float mean = stats[((size_t)b * GROUPS_ + g) * 2 + 0];
    const float rstd = stats[((size_t)b * GROUPS_ + g) * 2 + 1];
    const float sc = rstd * gnw[c];
    const float sh = gnb[c] - mean * sc;
    const float4 z  = *(const float4*)(Zg + idx);
    const float4 xv = *(const float4*)(xg + idx);
    float4 o;
    o.x = z.x * sc + sh + xv.x;
    o.y = z.y * sc + sh + xv.y;
    o.z = z.z * sc + sh + xv.z;
    o.w = z.w * sc + sh + xv.w;
    *(float4*)(out + idx) = o;
}

// ---------------------------------------------------------------------------
extern "C" void kernel_launch(void* const* d_in, const int* in_sizes, int n_in,
                              void* d_out, int out_size, void* d_ws, size_t ws_size,
                              hipStream_t stream)
{
    const float* x       = (const float*)d_in[0];
    const float* w_theta = (const float*)d_in[1];
    const float* b_theta = (const float*)d_in[2];
    const float* w_phi   = (const float*)d_in[3];
    const float* b_phi   = (const float*)d_in[4];
    const float* w_g     = (const float*)d_in[5];
    const float* b_g     = (const float*)d_in[6];
    const float* w_W     = (const float*)d_in[7];
    const float* b_W     = (const float*)d_in[8];
    const float* gn_w    = (const float*)d_in[9];
    const float* gn_b    = (const float*)d_in[10];
    float* out = (float*)d_out;
    char* wsb  = (char*)d_ws;

    // workspace layout (bytes)
    unsigned short* Q    = (unsigned short*)(wsb);             //  4,718,592
    unsigned short* K    = (unsigned short*)(wsb +  4718592);  //  1,179,648
    unsigned short* Vt   = (unsigned short*)(wsb +  5898240);  //  1,179,648
    unsigned short* phiF = (unsigned short*)(wsb +  7077888);  //  4,718,592
    unsigned short* gF   = (unsigned short*)(wsb + 11796480);  //  4,718,592
    float* Y             = (float*)(wsb +  7077888);           //  9,437,184 (aliases phiF+gF, dead after pool)
    float* Z             = (float*)(wsb + 16515072);           // 18,874,368
    float* stats         = (float*)(wsb + 35389440);           //  1 KB

    proj_kernel <<<dim3(HW_ / 32, B_, 3), 256, 0, stream>>>(
        x, w_theta, b_theta, w_phi, b_phi, w_g, b_g, Q, phiF, gF);
    pool_kernel <<<dim3(NP_ * CI_ / 256, B_, 2), 256, 0, stream>>>(phiF, gF, K, Vt);
    attn_kernel <<<dim3(HW_ / 32, B_), 256, 0, stream>>>(Q, K, Vt, Y);
    conv2_kernel<<<dim3(HW_ / 64, B_), 256, 0, stream>>>(Y, w_W, b_W, Z);
    stats_kernel<<<dim3(GROUPS_, B_), 256, 0, stream>>>(Z, stats);
    final_kernel<<<dim3((B_ * C_ * HW_) / 1024, 1), 256, 0, stream>>>(
        Z, x, stats, gn_w, gn_b, out);
}

// Round 8
// 165.467 us; speedup vs baseline: 1.4492x; 1.1024x over previous
//
#include <hip/hip_runtime.h>
#include <math.h>

#define B_ 4
#define C_ 128
#define CI_ 64
#define H_ 96
#define W_ 96
#define HW_ (H_*W_)      // 9216
#define NP_ 2304         // 48*48
#define GROUPS_ 32
#define EPS_ 1e-5f
#define NT_ 36           // KV tiles of 64

typedef _Float16 f16x8 __attribute__((ext_vector_type(8)));
typedef _Float16 f16x2 __attribute__((ext_vector_type(2)));
typedef __attribute__((ext_vector_type(4))) float f32x4;

__device__ inline f32x4 mfma16h(f16x8 a, f16x8 b, f32x4 c) {
    return __builtin_amdgcn_mfma_f32_16x16x32_f16(a, b, c, 0, 0, 0);
}
__device__ inline float h2f(unsigned short s) {
    return (float)__builtin_bit_cast(_Float16, s);
}
__device__ inline unsigned pk_f16(float a, float b) {     // pack 2 f32 -> 2 f16 (RTZ)
    return __builtin_bit_cast(unsigned, __builtin_amdgcn_cvt_pkrtz(a, b));
}
// global -> LDS direct DMA, 16B/lane. LDS dest is wave-uniform base + lane*16.
__device__ inline void gload_lds16(const void* g, void* l) {
    __builtin_amdgcn_global_load_lds(
        (const __attribute__((address_space(1))) void*)reinterpret_cast<uintptr_t>(g),
        (__attribute__((address_space(3))) void*)(unsigned)reinterpret_cast<uintptr_t>(l),
        16, 0, 0);
}

// ---------------------------------------------------------------------------
// Kernel 1: fused 3-way 1x1 conv projections -> fp16 [b][n][ci]
// ---------------------------------------------------------------------------
__global__ __launch_bounds__(256) void proj_kernel(
    const float* __restrict__ x,
    const float* __restrict__ w_theta, const float* __restrict__ b_theta,
    const float* __restrict__ w_phi,   const float* __restrict__ b_phi,
    const float* __restrict__ w_g,     const float* __restrict__ b_g,
    unsigned short* __restrict__ Qo, unsigned short* __restrict__ phiF,
    unsigned short* __restrict__ gF)
{
    __shared__ float xs[C_ * 32];   // xs[c*32 + pix]
    __shared__ float ws[C_ * 68];   // ws[c*68 + ci]
    const int t    = threadIdx.x;
    const int tile = blockIdx.x;
    const int b    = blockIdx.y;
    const int mat  = blockIdx.z;
    const float* wsel = (mat == 0) ? w_theta : (mat == 1) ? w_phi : w_g;
    const float* bsel = (mat == 0) ? b_theta : (mat == 1) ? b_phi : b_g;
    unsigned short* osel = (mat == 0) ? Qo : (mat == 1) ? phiF : gF;
    const int n0 = tile * 32;

    {
        const int pix = t & 31;
        const int c0  = t >> 5;
        const float* xb = x + (size_t)b * C_ * HW_ + n0 + pix;
        for (int c = c0; c < C_; c += 8)
            xs[c * 32 + pix] = xb[(size_t)c * HW_];
    }
    for (int j = t; j < CI_ * C_; j += 256)
        ws[(j & 127) * 68 + (j >> 7)] = wsel[j];
    __syncthreads();

    const int tp = (t & 7) * 4;
    const int tc = (t >> 3) * 2;
    float acc[4][2] = {};
    #pragma unroll 4
    for (int c = 0; c < C_; ++c) {
        const float4 xv = *(const float4*)&xs[c * 32 + tp];
        const float2 wv = *(const float2*)&ws[c * 68 + tc];
        const float xa[4] = {xv.x, xv.y, xv.z, xv.w};
        #pragma unroll
        for (int i = 0; i < 4; ++i) {
            acc[i][0] += xa[i] * wv.x;
            acc[i][1] += xa[i] * wv.y;
        }
    }
    const float2 bb = *(const float2*)&bsel[tc];
    #pragma unroll
    for (int i = 0; i < 4; ++i) {
        f16x2 hv = { (_Float16)(acc[i][0] + bb.x), (_Float16)(acc[i][1] + bb.y) };
        *(f16x2*)&osel[((size_t)b * HW_ + n0 + tp + i) * CI_ + tc] = hv;
    }
}

// ---------------------------------------------------------------------------
// Kernel 2: 2x2 maxpool (fp16 in/out, exact). K stays [b][m][ci]; V -> [b][ci][m].
// ---------------------------------------------------------------------------
__global__ __launch_bounds__(256) void pool_kernel(
    const unsigned short* __restrict__ phiF, const unsigned short* __restrict__ gF,
    unsigned short* __restrict__ Ko, unsigned short* __restrict__ Vt)
{
    const int t   = threadIdx.x;
    const int b   = blockIdx.y;
    const int mat = blockIdx.z;                 // 0 -> K, 1 -> V^T
    const int idx = blockIdx.x * 256 + t;       // 0..147455
    int m, ci;
    if (mat == 0) { m = idx >> 6; ci = idx & 63; }
    else          { ci = idx / NP_; m = idx - ci * NP_; }
    const int ph = m / 48, pw = m % 48;
    const int n00 = (ph * 2) * W_ + pw * 2;
    const unsigned short* src = mat ? gF : phiF;
    const unsigned short* p = src + ((size_t)b * HW_ + n00) * CI_ + ci;
    float v = fmaxf(fmaxf(h2f(p[0]), h2f(p[CI_])),
                    fmaxf(h2f(p[(size_t)W_ * CI_]), h2f(p[(size_t)(W_ + 1) * CI_])));
    unsigned short r = __builtin_bit_cast(unsigned short, (_Float16)v); // exact
    if (mat == 0) Ko[((size_t)b * NP_ + m) * CI_ + ci] = r;
    else          Vt[((size_t)b * CI_ + ci) * NP_ + m] = r;
}

// ---------------------------------------------------------------------------
// Kernel 3: fp16 MFMA flash attention — global_load_lds double-buffered staging.
// Block = 2 waves x 32 q-rows (64 rows). Grid 144x4 = 576 blocks, 4 blocks/CU.
// 2-phase schedule: stage(t+1) -> compute(t) -> vmcnt(0)+barrier (1 barrier/tile).
// Staging uses ZERO VGPRs (direct-to-LDS DMA) -> all 16x1KB loads in flight.
// Swizzle rule 21: linear LDS dest + inverse-swizzled GLOBAL source + XOR reads.
// K/V fragments read once per tile, shared by both q-subtiles.
// ---------------------------------------------------------------------------
__global__ __launch_bounds__(128) void attn_kernel(
    const unsigned short* __restrict__ Qg, const unsigned short* __restrict__ Kg,
    const unsigned short* __restrict__ Vt, float* __restrict__ Yg)
{
    __shared__ unsigned char lds_kv[2][2][8192];   // [buf][K/V][64 rows x 128B]
    __shared__ unsigned char PsB[2][16 * 144];     // per-wave P repack

    const int t    = threadIdx.x;
    const int wv   = t >> 6;
    const int lane = t & 63;
    const int lr   = lane & 15;
    const int lg   = lane >> 4;
    const int b    = blockIdx.y;
    const int q0   = blockIdx.x * 64 + wv * 32;

    // staging lane constants: lane l fills LDS slot (row=l>>3, chunk=l&7);
    // it must FETCH global chunk (l&7)^(row&7) of that row (inverse swizzle).
    const int srow = lane >> 3;                    // 0..7
    const int schk = (lane & 7) ^ (srow & 7);      // source 16B-chunk

    const unsigned short* Kb = Kg + (size_t)b * NP_ * CI_;
    const unsigned short* Vb = Vt + (size_t)b * CI_ * NP_;

    // Q fragments: qs in {0,1} sub-tiles, u in {0,1} k-steps
    f16x8 qf[2][2];
    #pragma unroll
    for (int qs = 0; qs < 2; ++qs)
        #pragma unroll
        for (int u = 0; u < 2; ++u)
            qf[qs][u] = *(const f16x8*)(Qg
                + ((size_t)b * HW_ + q0 + qs * 16 + lr) * CI_ + u * 32 + lg * 8);

    f32x4 o_acc[2][4];
    #pragma unroll
    for (int qs = 0; qs < 2; ++qs)
        #pragma unroll
        for (int dt = 0; dt < 4; ++dt)
            o_acc[qs][dt] = (f32x4){0.f, 0.f, 0.f, 0.f};
    float mrun[2] = {-1e30f, -1e30f};
    float lrun[2] = {0.f, 0.f};   // per-lane partial; reduced once at the end

    auto stage = [&](int tn) {
        const int buf = tn & 1;
        const int kv0 = tn * 64;
        if (wv == 0) {                              // wave 0 stages K tile
            #pragma unroll
            for (int i = 0; i < 8; ++i)
                gload_lds16(Kb + (size_t)(kv0 + 8 * i + srow) * CI_ + schk * 8,
                            &lds_kv[buf][0][i * 1024]);
        } else {                                    // wave 1 stages V^T tile
            #pragma unroll
            for (int i = 0; i < 8; ++i)
                gload_lds16(Vb + (size_t)(8 * i + srow) * NP_ + kv0 + schk * 8,
                            &lds_kv[buf][1][i * 1024]);
        }
    };

    stage(0);
    asm volatile("s_waitcnt vmcnt(0)" ::: "memory");
    __syncthreads();

    for (int tt = 0; tt < NT_; ++tt) {
        if (tt + 1 < NT_) stage(tt + 1);            // loads fly during compute

        const unsigned char* Ks = &lds_kv[tt & 1][0][0];
        const unsigned char* Vs = &lds_kv[tt & 1][1][0];

        // ---- K fragments once per tile (shared by both qs)
        f16x8 kf[2][4];
        #pragma unroll
        for (int u = 0; u < 2; ++u)
            #pragma unroll
            for (int k4 = 0; k4 < 4; ++k4)
                kf[u][k4] = *(const f16x8*)&Ks[(k4 * 16 + lr) * 128
                               + (((4 * u + lg) ^ (lr & 7)) << 4)];

        // ---- S^T for both q-subtiles (lane holds S[k=16k4+4lg+r][q=lr])
        f32x4 s0[4], s1[4];
        #pragma unroll
        for (int k4 = 0; k4 < 4; ++k4) {
            s0[k4] = (f32x4){0.f, 0.f, 0.f, 0.f};
            s1[k4] = (f32x4){0.f, 0.f, 0.f, 0.f};
        }
        __builtin_amdgcn_s_setprio(1);
        #pragma unroll
        for (int u = 0; u < 2; ++u)
            #pragma unroll
            for (int k4 = 0; k4 < 4; ++k4) {
                s0[k4] = mfma16h(kf[u][k4], qf[0][u], s0[k4]);
                s1[k4] = mfma16h(kf[u][k4], qf[1][u], s1[k4]);
            }
        __builtin_amdgcn_s_setprio(0);

        // ---- softmax per qs (independent chains); P -> LDS; pf back
        f16x8 pf[2][2];
        #pragma unroll
        for (int qs = 0; qs < 2; ++qs) {
            const f32x4* s = qs ? s1 : s0;
            float tmax = -1e30f;
            #pragma unroll
            for (int k4 = 0; k4 < 4; ++k4)
                tmax = fmaxf(tmax, fmaxf(fmaxf(s[k4][0], s[k4][1]),
                                         fmaxf(s[k4][2], s[k4][3])));
            tmax = fmaxf(tmax, __shfl_xor(tmax, 16));
            tmax = fmaxf(tmax, __shfl_xor(tmax, 32));

            if (!__all(tmax <= mrun[qs] + 8.0f)) {  // defer-max THR=8
                const float mnew = fmaxf(mrun[qs], tmax);
                const float sc = __expf(mrun[qs] - mnew);
                lrun[qs] *= sc;
                #pragma unroll
                for (int r2 = 0; r2 < 4; ++r2) {
                    const float scb = __shfl(sc, 4 * lg + r2);
                    #pragma unroll
                    for (int dt = 0; dt < 4; ++dt) o_acc[qs][dt][r2] *= scb;
                }
                mrun[qs] = mnew;
            }

            float psum = 0.f;
            #pragma unroll
            for (int k4 = 0; k4 < 4; ++k4) {
                const float e0 = __expf(s[k4][0] - mrun[qs]);
                const float e1 = __expf(s[k4][1] - mrun[qs]);
                const float e2 = __expf(s[k4][2] - mrun[qs]);
                const float e3 = __expf(s[k4][3] - mrun[qs]);
                psum += (e0 + e1) + (e2 + e3);
                uint2 pk = { pk_f16(e0, e1), pk_f16(e2, e3) };
                *(uint2*)&PsB[wv][lr * 144 + k4 * 32 + lg * 8] = pk;
            }
            lrun[qs] += psum;                       // per-lane partial (no shfl)

            #pragma unroll
            for (int u = 0; u < 2; ++u)
                pf[qs][u] = *(const f16x8*)&PsB[wv][lr * 144 + 64 * u + 16 * lg];
        }

        // ---- O += P * V (V fragments shared by both qs)
        __builtin_amdgcn_s_setprio(1);
        #pragma unroll
        for (int u = 0; u < 2; ++u)
            #pragma unroll
            for (int dt = 0; dt < 4; ++dt) {
                f16x8 vf = *(const f16x8*)&Vs[(dt * 16 + lr) * 128
                               + (((4 * u + lg) ^ (lr & 7)) << 4)];
                o_acc[0][dt] = mfma16h(pf[0][u], vf, o_acc[0][dt]);
                o_acc[1][dt] = mfma16h(pf[1][u], vf, o_acc[1][dt]);
            }
        __builtin_amdgcn_s_setprio(0);

        asm volatile("s_waitcnt vmcnt(0)" ::: "memory");  // stage(t+1) landed
        __syncthreads();                                  // all reads of buf done
    }

    // ---- finalize: reduce l across the 4 lane-copies, divide, store fp32
    #pragma unroll
    for (int qs = 0; qs < 2; ++qs) {
        float lt = lrun[qs];
        lt += __shfl_xor(lt, 16);
        lt += __shfl_xor(lt, 32);
        #pragma unroll
        for (int r2 = 0; r2 < 4; ++r2) {
            const float inv = 1.0f / __shfl(lt, 4 * lg + r2);
            const int q = q0 + qs * 16 + 4 * lg + r2;
            float* yp = Yg + ((size_t)b * HW_ + q) * CI_ + lr;
            #pragma unroll
            for (int dt = 0; dt < 4; ++dt)
                yp[dt * 16] = o_acc[qs][dt][r2] * inv;
        }
    }
}

// ---------------------------------------------------------------------------
// Kernel 4: 1x1 conv back to 128 channels (fp32).
// ---------------------------------------------------------------------------
__global__ __launch_bounds__(256) void conv2_kernel(
    const float* __restrict__ Yg, const float* __restrict__ wW,
    const float* __restrict__ bW, float* __restrict__ Zg)
{
    __shared__ float ys[CI_ * 68];
    __shared__ float ws2[CI_ * 132];
    const int t  = threadIdx.x;
    const int b  = blockIdx.y;
    const int n0 = blockIdx.x * 64;

    const float* ybase = Yg + ((size_t)b * HW_ + n0) * CI_;
    for (int j = t; j < 64 * CI_; j += 256)
        ys[(j & 63) * 68 + (j >> 6)] = ybase[j];
    for (int j = t; j < C_ * CI_; j += 256)
        ws2[(j & 63) * 132 + (j >> 6)] = wW[j];
    __syncthreads();

    const int tp = (t & 15) * 4;
    const int to = (t >> 4) * 8;
    float acc[4][8] = {};
    #pragma unroll 2
    for (int ci = 0; ci < CI_; ++ci) {
        const float4 yv  = *(const float4*)&ys[ci * 68 + tp];
        const float4 wv0 = *(const float4*)&ws2[ci * 132 + to];
        const float4 wv1 = *(const float4*)&ws2[ci * 132 + to + 4];
        const float ya[4] = {yv.x, yv.y, yv.z, yv.w};
        const float wa[8] = {wv0.x, wv0.y, wv0.z, wv0.w, wv1.x, wv1.y, wv1.z, wv1.w};
        #pragma unroll
        for (int i = 0; i < 4; ++i)
            #pragma unroll
            for (int j = 0; j < 8; ++j)
                acc[i][j] += ya[i] * wa[j];
    }
    #pragma unroll
    for (int j = 0; j < 8; ++j) {
        const int o = to + j;
        const float bb = bW[o];
        float* zp = Zg + ((size_t)b * C_ + o) * HW_ + n0 + tp;
        float4 v = { acc[0][j] + bb, acc[1][j] + bb, acc[2][j] + bb, acc[3][j] + bb };
        *(float4*)zp = v;
    }
}

// ---------------------------------------------------------------------------
// Kernel 5: GroupNorm stats (deterministic).
// ---------------------------------------------------------------------------
__global__ __launch_bounds__(256) void stats_kernel(
    const float* __restrict__ Zg, float* __restrict__ stats)
{
    const int t  = threadIdx.x;
    const int gr = blockIdx.x;
    const int b  = blockIdx.y;
    const float4* zp = (const float4*)(Zg + ((size_t)b * C_ + gr * 4) * HW_);
    float s = 0.f, ss = 0.f;
    for (int i = t; i < HW_; i += 256) {
        const float4 v = zp[i];
        s  += v.x + v.y + v.z + v.w;
        ss += v.x*v.x + v.y*v.y + v.z*v.z + v.w*v.w;
    }
    __shared__ float rs[256], rq[256];
    rs[t] = s; rq[t] = ss;
    __syncthreads();
    for (int off = 128; off > 0; off >>= 1) {
        if (t < off) { rs[t] += rs[t + off]; rq[t] += rq[t + off]; }
        __syncthreads();
    }
    if (t == 0) {
        const float invn = 1.0f / (4 * HW_);
        const float mean = rs[0] * invn;
        const float var  = rq[0] * invn - mean * mean;
        stats[((size_t)b * GROUPS_ + gr) * 2 + 0] = mean;
        stats[((size_t)b * GROUPS_ + gr) * 2 + 1] = rsqrtf(var + EPS_);
    }
}

// ---------------------------------------------------------------------------
// Kernel 6: normalize + affine + residual.
// ---------------------------------------------------------------------------
__global__ __launch_bounds__(256) void final_kernel(
    const float* __restrict__ Zg, const float* __restrict__ xg,
    const float* __restrict__ stats, const float* __restrict__ gnw,
    const float* __restrict__ gnb, float* __restrict__ out)
{
    const size_t i4  = (size_t)blockIdx.x * 256 + threadIdx.x;
    const size_t idx = i4 * 4;
    const int bc = (int)(i4 / (HW_ / 4));
    const int c  = bc & 127;
    const int b  = bc >> 7;
    const int g  = c >> 2;
    const float mean = stats[((size_t)b * GROUPS_ + g) * 2 + 0];
    const float rstd = stats[((size_t)b * GROUPS_ + g) * 2 + 1];
    const float sc = rstd * gnw[c];
    const float sh = gnb[c] - mean * sc;
    const float4 z  = *(const float4*)(Zg + idx);
    const float4 xv = *(const float4*)(xg + idx);
    float4 o;
    o.x = z.x * sc + sh + xv.x;
    o.y = z.y * sc + sh + xv.y;
    o.z = z.z * sc + sh + xv.z;
    o.w = z.w * sc + sh + xv.w;
    *(float4*)(out + idx) = o;
}

// ---------------------------------------------------------------------------
extern "C" void kernel_launch(void* const* d_in, const int* in_sizes, int n_in,
                              void* d_out, int out_size, void* d_ws, size_t ws_size,
                              hipStream_t stream)
{
    const float* x       = (const float*)d_in[0];
    const float* w_theta = (const float*)d_in[1];
    const float* b_theta = (const float*)d_in[2];
    const float* w_phi   = (const float*)d_in[3];
    const float* b_phi   = (const float*)d_in[4];
    const float* w_g     = (const float*)d_in[5];
    const float* b_g     = (const float*)d_in[6];
    const float* w_W     = (const float*)d_in[7];
    const float* b_W     = (const float*)d_in[8];
    const float* gn_w    = (const float*)d_in[9];
    const float* gn_b    = (const float*)d_in[10];
    float* out = (float*)d_out;
    char* wsb  = (char*)d_ws;

    // workspace layout (bytes)
    unsigned short* Q    = (unsigned short*)(wsb);             //  4,718,592
    unsigned short* K    = (unsigned short*)(wsb +  4718592);  //  1,179,648
    unsigned short* Vt   = (unsigned short*)(wsb +  5898240);  //  1,179,648
    unsigned short* phiF = (unsigned short*)(wsb +  7077888);  //  4,718,592
    unsigned short* gF   = (unsigned short*)(wsb + 11796480);  //  4,718,592
    float* Y             = (float*)(wsb +  7077888);           //  9,437,184 (aliases phiF+gF, dead after pool)
    float* Z             = (float*)(wsb + 16515072);           // 18,874,368
    float* stats         = (float*)(wsb + 35389440);           //  1 KB

    proj_kernel <<<dim3(HW_ / 32, B_, 3), 256, 0, stream>>>(
        x, w_theta, b_theta, w_phi, b_phi, w_g, b_g, Q, phiF, gF);
    pool_kernel <<<dim3(NP_ * CI_ / 256, B_, 2), 256, 0, stream>>>(phiF, gF, K, Vt);
    attn_kernel <<<dim3(HW_ / 64, B_), 128, 0, stream>>>(Q, K, Vt, Y);
    conv2_kernel<<<dim3(HW_ / 64, B_), 256, 0, stream>>>(Y, w_W, b_W, Z);
    stats_kernel<<<dim3(GROUPS_, B_), 256, 0, stream>>>(Z, stats);
    final_kernel<<<dim3((B_ * C_ * HW_) / 1024, 1), 256, 0, stream>>>(
        Z, x, stats, gn_w, gn_b, out);
}